// Round 9
// baseline (198.783 us; speedup 1.0000x reference)
//
#include <hip/hip_runtime.h>
#include <stdint.h>

// ---------------------------------------------------------------------------
// Binarized QAT CNN forward (R22 = R21 resubmit; R21 bench died infra-side
// ["container failed twice"], full audit found no bug — see below).
//   - R20 LESSON: +16 VGPR (8-ch weight hoist) dropped occupancy 50->39% and
//     REGRESSED 3% despite -27% conflicts. VGPR above ~44 costs more latency
//     hiding than LDS savings buy. Keep weight chunks at 4 ch (R19 form).
//   - R21/R22: phase-1 LDS cut WITHOUT VGPR cost — thread owns a vertical
//     3-px strip (26 cols x 9 row-groups = 234 threads); 5x3 shared window =
//     15 ds_read_b32/chunk vs 27 -> per-thread phase-1 reads 108 -> 60.
//     Per-px fma chain bit-identical: xw2[(s+r)*3+cc] == old xw[r*3+cc],
//     i ascending. AUDIT (R22): coverage rows 0..25 exact-once; clamp slot
//     r=4 only feeds s=2 which is guarded out for g=8; max read byte 13948
//     inside xs. Clean LDS-pipe-hypothesis test at controlled VGPR; if null,
//     bottleneck is barrier/latency structure (next: fuse phase 4 into 3).
//   - R18 LESSON kept: XOR-by-row-parity LDS swizzle is NON-BIJECTIVE at
//     non-128-mult row strides — do not re-add.
//   - k_prep_max unchanged. Remainder (total - k_forward) ~95 us is fixed
//     (prep + harness memset/launch chain); only k_forward is optimizable.
//
// HARNESS RULE (R12): hipLaunchCooperativeKernel silently fails under graph
// capture here. Two plain dispatches are the minimum; do not retry coop.
// RACE RULE (R8/R9, confirmed R10): the wsmax line (d_ws bytes 0..255) is
// touched ONLY by signed atomicMax (0xAA poison is negative -> loses, so no
// zeroing store exists anywhere); all prep plain-stores live at byte >= 256.
// Slots 0..31 all atomic-only; untouched slots stay poison (negative float,
// loses the fmax reduce in k_forward).
// NUMERICS RULE (R8): conv1 must keep the exact pk-fma form (h += w*s,
// i ascending, LDS-staged weight values) in BOTH kernels — scalar-chain
// rewrites flip boundary decisions.
// NOTE: plain __launch_bounds__(256) — a min-waves arg caps arch VGPRs and
// spills ~50 dw/thread (R4: 426 MB scratch writes). Do not re-add it.
//
// MFMA i8 16x16x64 lane mapping (gfx950): A: lane l holds A[m=l&15][k=16q+j];
// B: B[k=16q+j][n=l&15]; D reg r: row=(l>>4)*4+r, col=l&15. A=weights =>
// A-row oc = col; lane's 4 D values = 4 consecutive channels of one pixel.
// K=144 padded to 192 by zeroing the WEIGHT fragment for k-blocks 9..11.
//
// d_ws layout (dwords): [0..31] wsmax slots (atomic-only line) |
//   [64..73] badj f32[10] | [80..95] rs2 | [96..127] rs3 | [128..703] w2m |
//   [704..1855] w3m | [1856..11535] sw   (total 46144 B)
//
// k_forward LDS map (20456 B, 8 blocks/CU):
//   a1 [0, 10816): 26x26 px x 16 B; p4 [121 cells x 48 B = 5808 B] aliases
//     head (a1 dead in phases 3+).
//   h2 [10816, 20416): 24 rows x 25 px x 16 B (col 24 = pad); xs [3136 B] +
//     w1t [576 B] alias head during phases 0-1.
//   out_acc @20416 (40 B).
// ---------------------------------------------------------------------------

typedef int int4v __attribute__((ext_vector_type(4)));
typedef float f2 __attribute__((ext_vector_type(2)));

__device__ __forceinline__ int4v mfma_i8(int4v a, int4v b, int4v c) {
  return __builtin_amdgcn_mfma_i32_16x16x64_i8(a, b, c, 0, 0, 0);
}

__device__ __forceinline__ int dot4(int a, int b, int c) {
#if __has_builtin(__builtin_amdgcn_sdot4)
  return __builtin_amdgcn_sdot4(a, b, c, false);
#else
  int r = c;
  r += (int)(int8_t)(a)       * (int)(int8_t)(b);
  r += (int)(int8_t)(a >> 8)  * (int)(int8_t)(b >> 8);
  r += (int)(int8_t)(a >> 16) * (int)(int8_t)(b >> 16);
  r += (int)(int8_t)(a >> 24) * (int)(int8_t)(b >> 24);
  return r;
#endif
}

// Pack low bytes of r0..r3 into one dword: [r0b0|r1b0|r2b0|r3b0].
__device__ __forceinline__ int pack4(int r0, int r1, int r2, int r3) {
  const int t0 = __builtin_amdgcn_perm(r1, r0, 0x00000400);
  const int t1 = __builtin_amdgcn_perm(r3, r2, 0x00000400);
  return __builtin_amdgcn_perm(t1, t0, 0x05040100);
}

// med3(v,0,2) in one VALU op; acc init carries the +1 so this is the epilogue.
__device__ __forceinline__ int cl02(int v) {
  int r;
  asm("v_med3_i32 %0, %1, 0, 2" : "=v"(r) : "v"(v));
  return r;
}

__device__ __forceinline__ int sgn_pack_byte(float v) {
  return (v > 0.f) - (v < 0.f);
}

// Dispatch 1 -- merged conv1-max + prep (unchanged from R15).
__global__ __launch_bounds__(256) void k_prep_max(
    const float* __restrict__ x, const float* __restrict__ w1,
    const float* __restrict__ w2, const float* __restrict__ w3,
    const float* __restrict__ wfc, const float* __restrict__ bfc,
    int* __restrict__ ws, int B, int NMAX) {
  __shared__ __align__(16) float xs[1568];
  __shared__ __align__(8) float w1t[144];
  __shared__ float wred[4];
  __shared__ int part[4];

  const int tid = threadIdx.x;
  if ((int)blockIdx.x < NMAX) {
    const int img0 = blockIdx.x * 2;
    const bool has1 = (img0 + 1) < B;
    {
      const float4* x4a = (const float4*)(x + (size_t)img0 * 784);
      const float4* x4b = (const float4*)(x + (size_t)(img0 + (int)has1) * 784);
      for (int u = tid; u < 392; u += 256) {
        const int im = (u >= 196), i = im ? u - 196 : u;
        const float4 v = im ? x4b[i] : x4a[i];
        *(float4*)&xs[im * 784 + i * 4] = v;
      }
    }
    if (tid < 144) w1t[(tid % 9) * 16 + tid / 9] = w1[tid];
    __syncthreads();
    const f2* w1t2 = (const f2*)w1t;
    const float* xs0 = xs;
    const float* xs1 = xs + 784;
    float m = 0.f;
    for (int px = tid; px < 676; px += 256) {
      const int oy = px / 26, ox = px - oy * 26;
      float xw0[9], xw1[9];
#pragma unroll
      for (int r = 0; r < 3; ++r)
#pragma unroll
        for (int cc = 0; cc < 3; ++cc) {
          const int ix = (oy + r) * 28 + ox + cc;
          xw0[r * 3 + cc] = xs0[ix];
          xw1[r * 3 + cc] = xs1[ix];
        }
#pragma unroll
      for (int cw = 0; cw < 8; ++cw) {
        f2 h0 = {0.f, 0.f}, h1 = {0.f, 0.f};
#pragma unroll
        for (int i = 0; i < 9; ++i) {
          const f2 w = w1t2[i * 8 + cw];
          const f2 s0 = {xw0[i], xw0[i]};
          const f2 s1 = {xw1[i], xw1[i]};
          h0 += w * s0;
          h1 += w * s1;
        }
        m = fmaxf(m, fmaxf(fmaxf(fabsf(h0.x), fabsf(h0.y)),
                           fmaxf(fabsf(h1.x), fabsf(h1.y))));
      }
    }
#pragma unroll
    for (int off = 32; off; off >>= 1) m = fmaxf(m, __shfl_down(m, off, 64));
    if ((tid & 63) == 0) wred[tid >> 6] = m;
    __syncthreads();
    if (tid == 0) {
      const float mm = fmaxf(fmaxf(wred[0], wred[1]), fmaxf(wred[2], wred[3]));
      atomicMax(ws + ((int)blockIdx.x & 31), (int)__float_as_uint(mm));
    }
    return;
  }

  const int pb = blockIdx.x - NMAX;  // prep block id 0..55
  if (pb < 10) {
    const int j = pb;
    int s = 0;
    for (int i = tid; i < 3872; i += 256) {
      const float v = wfc[j * 3872 + i];
      s += (v > 0.f) - (v < 0.f);
    }
#pragma unroll
    for (int off = 32; off; off >>= 1) s += __shfl_down(s, off, 64);
    if ((tid & 63) == 0) part[tid >> 6] = s;
    __syncthreads();
    if (tid == 0) {
      const int rs = part[0] + part[1] + part[2] + part[3];
      ((float*)ws)[64 + j] = bfc[j] - (float)rs;  // badj @ dword 64 (byte 256)
    }
    if (pb == 1 && tid < 16) {  // rs2[oc] @ dword 80
      int s2 = 0;
      for (int i = 0; i < 144; ++i) s2 += sgn_pack_byte(w2[tid * 144 + i]);
      ws[80 + tid] = s2;
    }
    if (pb == 2 && tid < 32) {  // rs3[oc] @ dword 96
      int s3 = 0;
      for (int i = 0; i < 144; ++i) s3 += sgn_pack_byte(w3[tid * 144 + i]);
      ws[96 + tid] = s3;
    }
    return;
  }
  int* dst = ws + 128;
  const int widx = (pb - 10) * 256 + tid;
  if (widx < 576) {  // w2m: dword = oc*36 + wp*4 + icg
    const int oc = widx / 36, r = widx % 36, wp = r >> 2, icg = r & 3;
    unsigned wrd = 0;
#pragma unroll
    for (int b = 0; b < 4; ++b) {
      const float v = w2[(oc * 16 + icg * 4 + b) * 9 + wp];
      wrd |= ((unsigned)(uint8_t)(int8_t)sgn_pack_byte(v)) << (8 * b);
    }
    dst[widx] = (int)wrd;
  } else if (widx < 1728) {  // w3m
    const int t = widx - 576;
    const int oc = t / 36, r = t % 36, wp = r >> 2, icg = r & 3;
    unsigned wrd = 0;
#pragma unroll
    for (int b = 0; b < 4; ++b) {
      const float v = w3[(oc * 16 + icg * 4 + b) * 9 + wp];
      wrd |= ((unsigned)(uint8_t)(int8_t)sgn_pack_byte(v)) << (8 * b);
    }
    dst[widx] = (int)wrd;
  } else if (widx < 11408) {  // sw: dword = j*968 + pos*8 + cg
    const int t = widx - 1728;
    const int j = t / 968, r = t % 968, pos = r >> 3, cg = r & 7;
    unsigned wrd = 0;
#pragma unroll
    for (int b = 0; b < 4; ++b) {
      const float v = wfc[j * 3872 + (cg * 4 + b) * 121 + pos];
      wrd |= ((unsigned)(uint8_t)(int8_t)sgn_pack_byte(v)) << (8 * b);
    }
    dst[widx] = (int)wrd;
  }
}

// ---------------------------------------------------------------------------
// Dispatch 2 -- k_forward: ONE image per block. LDS 20456 B -> 8 blocks/CU.
// ---------------------------------------------------------------------------
__global__ __launch_bounds__(256) void k_forward(
    const float* __restrict__ x, const float* __restrict__ w1,
    const int* __restrict__ wsd,  // d_ws base (dword-indexed)
    float* __restrict__ out, int B) {
  __shared__ __align__(16) char smem[20456];
  int* out_acc = (int*)(smem + 20416);  // [10]

  const int* wpack = wsd + 128;          // w2m | w3m (w3m at wpack+576)
  const int* sw = wsd + 1856;            // [10][968] dw
  const float* badj = (const float*)(wsd + 64);

  const int tid = threadIdx.x;
  const int img = blockIdx.x;

  // Early: this lane's wsmax slot (atomic-only line; poison is negative).
  const float slotv = __uint_as_float((unsigned)wsd[tid & 31]);

  // Stage: x -> xs @10816 via float4 (196 f4), w1t @13952, out_acc.
  {
    const float4* x4 = (const float4*)(x + (size_t)img * 784);
    if (tid < 196) *(float4*)(smem + 10816 + tid * 16) = x4[tid];
  }
  if (tid < 144) *(float*)(smem + 13952 + ((tid % 9) * 16 + tid / 9) * 4) = w1[tid];
  if (tid < 10) out_acc[tid] = 0;
  __syncthreads();

  // Phase 1: conv1 -> a1 = (s+1) in {0,1,2}. Vertical 3-px strips: thread =
  // (col ox, row-group g), 26x9 = 234 active; 5x3 window (15 loads) shared
  // by the 3 px; 4 chunks of 4 channels (R19 weight form, low VGPR).
  // Per-px chain bit-identical: xw2[(s+r)*3+cc] == old xw[r*3+cc].
  // Scale = wave-butterfly max over the 32 slots (fmax reorder is exact).
  float mraw = slotv;
#pragma unroll
  for (int off = 16; off; off >>= 1) mraw = fmaxf(mraw, __shfl_xor(mraw, off, 64));
  const float scale = mraw / 127.0f + 1e-8f;
  const float thr = 0.5f * scale;
  {
    const f2* w1t2 = (const f2*)(smem + 13952);
    const bool pact = tid < 234;
    const int ox = pact ? (tid % 26) : 0;
    const int g = pact ? (tid / 26) : 0;
    const int oy0 = g * 3;
    const int npx = pact ? ((oy0 <= 23) ? 3 : 26 - oy0) : 0;  // g=8 -> 2
    const char* bx = smem + 10816 + (oy0 * 28 + ox) * 4;
    // row r=4 clamp (g=8 would touch input row 28; clamped value feeds only
    // the guarded-out 3rd px)
    const int r4 = (oy0 + 4 < 28) ? 4 : 3;
    unsigned wq[3][4];
#pragma unroll
    for (int ch = 0; ch < 4; ++ch) {
      f2 wa[9], wb9[9];
#pragma unroll
      for (int i = 0; i < 9; ++i) {
        wa[i] = w1t2[i * 8 + 2 * ch];      // channels 4ch+0,4ch+1
        wb9[i] = w1t2[i * 8 + 2 * ch + 1]; // channels 4ch+2,4ch+3
      }
      if (pact) {
        float xw2[15];
#pragma unroll
        for (int r = 0; r < 5; ++r) {
          const int rr = (r < 4) ? r : r4;
#pragma unroll
          for (int c = 0; c < 3; ++c)
            xw2[r * 3 + c] = *(const float*)(bx + (rr * 28 + c) * 4);
        }
#pragma unroll
        for (int s = 0; s < 3; ++s) {
          if (s < npx) {
            f2 h0 = {0.f, 0.f}, h1 = {0.f, 0.f};
#pragma unroll
            for (int i = 0; i < 9; ++i) {
              const f2 sv = {xw2[s * 3 + i], xw2[s * 3 + i]};
              h0 += wa[i] * sv;
              h1 += wb9[i] * sv;
            }
            // (s+1): 0 iff h < -thr, 1 iff |h| <= thr, 2 iff h > thr.
            wq[s][ch] = (unsigned)pack4(
                (h0.x >= -thr) + (h0.x > thr), (h0.y >= -thr) + (h0.y > thr),
                (h1.x >= -thr) + (h1.x > thr), (h1.y >= -thr) + (h1.y > thr));
          }
        }
      }
    }
#pragma unroll
    for (int s = 0; s < 3; ++s)
      if (s < npx)
        *(int4*)(smem + ((oy0 + s) * 26 + ox) * 16) =
            make_int4((int)wq[s][0], (int)wq[s][1], (int)wq[s][2], (int)wq[s][3]);
  }
  __syncthreads();

  // MFMA lane geometry. t=2 uses wp=8 for ALL quads (dead-B broadcast:
  // quads 1-3 have zero-A so values are ignored; same-address read is free
  // and keeps the operand inside the live region).
  const int lane = tid & 63, wv = tid >> 6;
  const int col = lane & 15, quad = lane >> 4;
  int off2[3], off3[3];
#pragma unroll
  for (int t = 0; t < 3; ++t) {
    const int wp = (t < 2) ? (t * 4 + quad) : 8;
    const int wr = wp / 3, wc = wp - wr * 3;
    off2[t] = (wr * 26 + wc) * 16;  // a1 stride 26 px
    off3[t] = (wr * 25 + wc) * 16;  // h2 stride 25 px
  }
  const bool kq0 = (quad == 0);

  // Phase 2: conv2. A=sign(w2) frags; acc init = 1 - rs2 (the +1 feeds cl02).
  // h2 written with padded row stride 25 px (400 B).
  {
    const int* wb = wpack + col * 36;  // A-row oc = col
    int4v WA[3];
    WA[0] = *(const int4v*)(wb + quad * 4);
    WA[1] = *(const int4v*)(wb + 16 + quad * 4);
    WA[2] = kq0 ? *(const int4v*)(wb + 32) : (int4v){0, 0, 0, 0};
    const int4v acc0 = (int4v){1, 1, 1, 1} - *(const int4v*)(wsd + 80 + quad * 4);
    const int8_t* a1b = (const int8_t*)smem;
    // incremental (oy,ox) over output pixel p = nt*16+col, nt += 4 (p += 64)
    const int p0 = wv * 16 + col;
    int oy = p0 / 24, ox = p0 - oy * 24;
    const int8_t* abase = a1b + (oy * 26 + ox) * 16;
    int* h2p = (int*)smem + 2704 + (oy * 25 + ox) * 4 + quad;
    for (int it = 0; it < 9; ++it) {
      int4v acc = acc0;
      acc = mfma_i8(WA[0], *(const int4v*)(abase + off2[0]), acc);
      acc = mfma_i8(WA[1], *(const int4v*)(abase + off2[1]), acc);
      acc = mfma_i8(WA[2], *(const int4v*)(abase + off2[2]), acc);
      *h2p = pack4(cl02(acc[0]), cl02(acc[1]), cl02(acc[2]), cl02(acc[3]));
      abase += 1088;  // a1: (oy+=2, ox+=16), stride 26
      h2p += 264;     // h2: (oy+=2, ox+=16), stride 25 (dwords)
      ox += 16;
      if (ox >= 24) { ox -= 24; abase += 32; h2p += 4; }
    }
  }
  __syncthreads();

  // Phase 3: conv3 + in-register pool. Pixels tiled pool-quad-major:
  // tile pt covers cells 4pt..4pt+3; lane col -> cell 4pt+(col>>2), sub col&3.
  // p4 (48 B/cell stride) is written into the a1 region (a1 dead).
  {
    int4v WA[2][3];
    int4v ac0[2];
#pragma unroll
    for (int ot = 0; ot < 2; ++ot) {
      const int* wb = wpack + 576 + (ot * 16 + col) * 36;
      WA[ot][0] = *(const int4v*)(wb + quad * 4);
      WA[ot][1] = *(const int4v*)(wb + 16 + quad * 4);
      WA[ot][2] = kq0 ? *(const int4v*)(wb + 32) : (int4v){0, 0, 0, 0};
      ac0[ot] = (int4v){1, 1, 1, 1} - *(const int4v*)(wsd + 96 + ot * 16 + quad * 4);
    }
    const int sub = col & 3;
    const int sy = sub >> 1, sx = sub & 1;
    const int cell0 = wv * 4 + (col >> 2);
    const int cy0 = cell0 / 11, cx0 = cell0 - cy0 * 11;
    const int aoff0 = ((cy0 * 2 + sy) * 25 + cx0 * 2 + sx) * 16;
    const int pb0 = cell0 * 12 + quad;
    const int aoffcap = ((20 + sy) * 25 + 20 + sx) * 16;  // cell 120 clamp
    const int pbcap = 120 * 12 + quad;
    const bool wlane = (sub == 0);
    const int8_t* h2b = (const int8_t*)(smem + 10816);
    int* p4 = (int*)smem;
    int aoff = aoff0, pb = pb0, cx = cx0;
    for (int pt = wv; pt < 31; pt += 4) {
      const int8_t* abase = h2b + ((aoff < aoffcap) ? aoff : aoffcap);
      const int pbu = (pb < pbcap) ? pb : pbcap;
      const int4v B0 = *(const int4v*)(abase + off3[0]);
      const int4v B1 = *(const int4v*)(abase + off3[1]);
      const int4v B2 = *(const int4v*)(abase + off3[2]);
#pragma unroll
      for (int ot = 0; ot < 2; ++ot) {
        int4v acc = ac0[ot];
        acc = mfma_i8(WA[ot][0], B0, acc);
        acc = mfma_i8(WA[ot][1], B1, acc);
        acc = mfma_i8(WA[ot][2], B2, acc);
        int s = pack4(cl02(acc[0]), cl02(acc[1]), cl02(acc[2]), cl02(acc[3]));
        // sum (s3+1) packed bytes across the lane nibble (cell's 2x2)
        s += __builtin_amdgcn_update_dpp(0, s, 0xB1, 0xF, 0xF, false);
        s += __builtin_amdgcn_update_dpp(0, s, 0x4E, 0xF, 0xF, false);
        if (wlane) p4[pbu + ot * 4] = s;
      }
      aoff += 960;  // cell += 16: (cy+=1, cx+=5), stride 25
      pb += 192;    // cell += 16, stride 12 dw
      cx += 5;
      if (cx >= 11) { cx -= 11; aoff += 448; }
    }
  }
  __syncthreads();

  // Phase 4: FC. acc = sum n*sw = 4*true + 4*rowsum(sw); badj corrects.
  // Mapping j=u%10, k=u/10: 10 lanes share each pos (LDS broadcast reads,
  // conflict-free with the 48 B cell stride); atomics 7-way per out_acc[j].
  if (tid < 250) {
    const int j = tid % 10, k = tid / 10;
    const int* p4d = (const int*)smem;
    int acc = 0;
    for (int pos = k; pos < 121; pos += 25) {
      const int4 pa = *(const int4*)(p4d + pos * 12);
      const int4 pb = *(const int4*)(p4d + pos * 12 + 4);
      const int* swr = sw + j * 968 + pos * 8;
      const int4 wa = *(const int4*)(swr);
      const int4 wbv = *(const int4*)(swr + 4);
      acc = dot4(pa.x, wa.x, acc);
      acc = dot4(pa.y, wa.y, acc);
      acc = dot4(pa.z, wa.z, acc);
      acc = dot4(pa.w, wa.w, acc);
      acc = dot4(pb.x, wbv.x, acc);
      acc = dot4(pb.y, wbv.y, acc);
      acc = dot4(pb.z, wbv.z, acc);
      acc = dot4(pb.w, wbv.w, acc);
    }
    atomicAdd(&out_acc[j], acc);
  }
  __syncthreads();
  if (tid < 10)
    out[(size_t)img * 10 + tid] = 0.25f * (float)out_acc[tid] + badj[tid];
}

extern "C" void kernel_launch(void* const* d_in, const int* in_sizes, int n_in,
                              void* d_out, int out_size, void* d_ws, size_t ws_size,
                              hipStream_t stream) {
  const float* x   = (const float*)d_in[0];
  const float* w1  = (const float*)d_in[1];
  const float* w2  = (const float*)d_in[2];
  const float* w3  = (const float*)d_in[3];
  const float* wfc = (const float*)d_in[4];
  const float* bfc = (const float*)d_in[5];
  float* out = (float*)d_out;
  int* wsd = (int*)d_ws;
  const int B = in_sizes[0] / 784;
  const int NMAX = (B + 1) / 2;

  hipLaunchKernelGGL(k_prep_max, dim3(NMAX + 56), dim3(256), 0, stream,
                     x, w1, w2, w3, wfc, bfc, wsd, B, NMAX);
  hipLaunchKernelGGL(k_forward, dim3(B), dim3(256), 0, stream, x, w1,
                     (const int*)wsd, out, B);
}

// Round 10
// 195.751 us; speedup vs baseline: 1.0155x; 1.0155x over previous
//
#include <hip/hip_runtime.h>
#include <stdint.h>

// ---------------------------------------------------------------------------
// Binarized QAT CNN forward (R23 = R22 + unrolled closed-form-address loops).
//   - BOTTLENECK MODEL (R22 post-mortem): VALU-cut null (R19), LDS-cut null
//     (R20/R22), conflicts 12M->9M no effect. Static issue ~30% of wall but
//     MfmaUtil 17% matches static MFMA exactly -> ~70% of cycles are
//     zero-issue STALLS (post-barrier LDS-latency convoys). The phase-2/3/4
//     loops were rolled with serial carried addresses (if(ox>=24) chains),
//     blocking software pipelining of their fully-independent iterations.
//   - R23: closed-form per-iteration addresses + #pragma unroll:
//     phase 2: p = p0+64*it (proven equal to incremental chain);
//     phase 3: cell = cell0+16u, ce = min(cell,120) (proven equal to the
//     old aoff/pb caps); phase 4: pos = k+25m guarded (pos<121 reproduces
//     the 4/5-trip variation). Arithmetic per output bit-identical.
//   - R20 LESSON: VGPR budget — stay ~<=64 (waves/SIMD = 512/VGPR-ish).
//   - R18 LESSON: XOR-by-row-parity LDS swizzle non-bijective at non-128-mult
//     strides — do not re-add.
//   - k_prep_max unchanged. Remainder (total - k_forward) ~95 us = reset()
//     memset dispatch chain + prep; fixed from our side.
//
// HARNESS RULE (R12): hipLaunchCooperativeKernel silently fails under graph
// capture here. Two plain dispatches are the minimum; do not retry coop.
// RACE RULE (R8/R9, confirmed R10): the wsmax line (d_ws bytes 0..255) is
// touched ONLY by signed atomicMax (0xAA poison is negative -> loses, so no
// zeroing store exists anywhere); all prep plain-stores live at byte >= 256.
// Slots 0..31 all atomic-only; untouched slots stay poison (negative float,
// loses the fmax reduce in k_forward).
// NUMERICS RULE (R8): conv1 must keep the exact pk-fma form (h += w*s,
// i ascending, LDS-staged weight values) in BOTH kernels — scalar-chain
// rewrites flip boundary decisions.
// NOTE: plain __launch_bounds__(256) — a min-waves arg caps arch VGPRs and
// spills ~50 dw/thread (R4: 426 MB scratch writes). Do not re-add it.
//
// MFMA i8 16x16x64 lane mapping (gfx950): A: lane l holds A[m=l&15][k=16q+j];
// B: B[k=16q+j][n=l&15]; D reg r: row=(l>>4)*4+r, col=l&15. A=weights =>
// A-row oc = col; lane's 4 D values = 4 consecutive channels of one pixel.
// K=144 padded to 192 by zeroing the WEIGHT fragment for k-blocks 9..11.
//
// d_ws layout (dwords): [0..31] wsmax slots (atomic-only line) |
//   [64..73] badj f32[10] | [80..95] rs2 | [96..127] rs3 | [128..703] w2m |
//   [704..1855] w3m | [1856..11535] sw   (total 46144 B)
//
// k_forward LDS map (20456 B, 8 blocks/CU):
//   a1 [0, 10816): 26x26 px x 16 B; p4 [121 cells x 48 B = 5808 B] aliases
//     head (a1 dead in phases 3+).
//   h2 [10816, 20416): 24 rows x 25 px x 16 B (col 24 = pad); xs [3136 B] +
//     w1t [576 B] alias head during phases 0-1.
//   out_acc @20416 (40 B).
// ---------------------------------------------------------------------------

typedef int int4v __attribute__((ext_vector_type(4)));
typedef float f2 __attribute__((ext_vector_type(2)));

__device__ __forceinline__ int4v mfma_i8(int4v a, int4v b, int4v c) {
  return __builtin_amdgcn_mfma_i32_16x16x64_i8(a, b, c, 0, 0, 0);
}

__device__ __forceinline__ int dot4(int a, int b, int c) {
#if __has_builtin(__builtin_amdgcn_sdot4)
  return __builtin_amdgcn_sdot4(a, b, c, false);
#else
  int r = c;
  r += (int)(int8_t)(a)       * (int)(int8_t)(b);
  r += (int)(int8_t)(a >> 8)  * (int)(int8_t)(b >> 8);
  r += (int)(int8_t)(a >> 16) * (int)(int8_t)(b >> 16);
  r += (int)(int8_t)(a >> 24) * (int)(int8_t)(b >> 24);
  return r;
#endif
}

// Pack low bytes of r0..r3 into one dword: [r0b0|r1b0|r2b0|r3b0].
__device__ __forceinline__ int pack4(int r0, int r1, int r2, int r3) {
  const int t0 = __builtin_amdgcn_perm(r1, r0, 0x00000400);
  const int t1 = __builtin_amdgcn_perm(r3, r2, 0x00000400);
  return __builtin_amdgcn_perm(t1, t0, 0x05040100);
}

// med3(v,0,2) in one VALU op; acc init carries the +1 so this is the epilogue.
__device__ __forceinline__ int cl02(int v) {
  int r;
  asm("v_med3_i32 %0, %1, 0, 2" : "=v"(r) : "v"(v));
  return r;
}

__device__ __forceinline__ int sgn_pack_byte(float v) {
  return (v > 0.f) - (v < 0.f);
}

// Dispatch 1 -- merged conv1-max + prep (unchanged from R15).
__global__ __launch_bounds__(256) void k_prep_max(
    const float* __restrict__ x, const float* __restrict__ w1,
    const float* __restrict__ w2, const float* __restrict__ w3,
    const float* __restrict__ wfc, const float* __restrict__ bfc,
    int* __restrict__ ws, int B, int NMAX) {
  __shared__ __align__(16) float xs[1568];
  __shared__ __align__(8) float w1t[144];
  __shared__ float wred[4];
  __shared__ int part[4];

  const int tid = threadIdx.x;
  if ((int)blockIdx.x < NMAX) {
    const int img0 = blockIdx.x * 2;
    const bool has1 = (img0 + 1) < B;
    {
      const float4* x4a = (const float4*)(x + (size_t)img0 * 784);
      const float4* x4b = (const float4*)(x + (size_t)(img0 + (int)has1) * 784);
      for (int u = tid; u < 392; u += 256) {
        const int im = (u >= 196), i = im ? u - 196 : u;
        const float4 v = im ? x4b[i] : x4a[i];
        *(float4*)&xs[im * 784 + i * 4] = v;
      }
    }
    if (tid < 144) w1t[(tid % 9) * 16 + tid / 9] = w1[tid];
    __syncthreads();
    const f2* w1t2 = (const f2*)w1t;
    const float* xs0 = xs;
    const float* xs1 = xs + 784;
    float m = 0.f;
    for (int px = tid; px < 676; px += 256) {
      const int oy = px / 26, ox = px - oy * 26;
      float xw0[9], xw1[9];
#pragma unroll
      for (int r = 0; r < 3; ++r)
#pragma unroll
        for (int cc = 0; cc < 3; ++cc) {
          const int ix = (oy + r) * 28 + ox + cc;
          xw0[r * 3 + cc] = xs0[ix];
          xw1[r * 3 + cc] = xs1[ix];
        }
#pragma unroll
      for (int cw = 0; cw < 8; ++cw) {
        f2 h0 = {0.f, 0.f}, h1 = {0.f, 0.f};
#pragma unroll
        for (int i = 0; i < 9; ++i) {
          const f2 w = w1t2[i * 8 + cw];
          const f2 s0 = {xw0[i], xw0[i]};
          const f2 s1 = {xw1[i], xw1[i]};
          h0 += w * s0;
          h1 += w * s1;
        }
        m = fmaxf(m, fmaxf(fmaxf(fabsf(h0.x), fabsf(h0.y)),
                           fmaxf(fabsf(h1.x), fabsf(h1.y))));
      }
    }
#pragma unroll
    for (int off = 32; off; off >>= 1) m = fmaxf(m, __shfl_down(m, off, 64));
    if ((tid & 63) == 0) wred[tid >> 6] = m;
    __syncthreads();
    if (tid == 0) {
      const float mm = fmaxf(fmaxf(wred[0], wred[1]), fmaxf(wred[2], wred[3]));
      atomicMax(ws + ((int)blockIdx.x & 31), (int)__float_as_uint(mm));
    }
    return;
  }

  const int pb = blockIdx.x - NMAX;  // prep block id 0..55
  if (pb < 10) {
    const int j = pb;
    int s = 0;
    for (int i = tid; i < 3872; i += 256) {
      const float v = wfc[j * 3872 + i];
      s += (v > 0.f) - (v < 0.f);
    }
#pragma unroll
    for (int off = 32; off; off >>= 1) s += __shfl_down(s, off, 64);
    if ((tid & 63) == 0) part[tid >> 6] = s;
    __syncthreads();
    if (tid == 0) {
      const int rs = part[0] + part[1] + part[2] + part[3];
      ((float*)ws)[64 + j] = bfc[j] - (float)rs;  // badj @ dword 64 (byte 256)
    }
    if (pb == 1 && tid < 16) {  // rs2[oc] @ dword 80
      int s2 = 0;
      for (int i = 0; i < 144; ++i) s2 += sgn_pack_byte(w2[tid * 144 + i]);
      ws[80 + tid] = s2;
    }
    if (pb == 2 && tid < 32) {  // rs3[oc] @ dword 96
      int s3 = 0;
      for (int i = 0; i < 144; ++i) s3 += sgn_pack_byte(w3[tid * 144 + i]);
      ws[96 + tid] = s3;
    }
    return;
  }
  int* dst = ws + 128;
  const int widx = (pb - 10) * 256 + tid;
  if (widx < 576) {  // w2m: dword = oc*36 + wp*4 + icg
    const int oc = widx / 36, r = widx % 36, wp = r >> 2, icg = r & 3;
    unsigned wrd = 0;
#pragma unroll
    for (int b = 0; b < 4; ++b) {
      const float v = w2[(oc * 16 + icg * 4 + b) * 9 + wp];
      wrd |= ((unsigned)(uint8_t)(int8_t)sgn_pack_byte(v)) << (8 * b);
    }
    dst[widx] = (int)wrd;
  } else if (widx < 1728) {  // w3m
    const int t = widx - 576;
    const int oc = t / 36, r = t % 36, wp = r >> 2, icg = r & 3;
    unsigned wrd = 0;
#pragma unroll
    for (int b = 0; b < 4; ++b) {
      const float v = w3[(oc * 16 + icg * 4 + b) * 9 + wp];
      wrd |= ((unsigned)(uint8_t)(int8_t)sgn_pack_byte(v)) << (8 * b);
    }
    dst[widx] = (int)wrd;
  } else if (widx < 11408) {  // sw: dword = j*968 + pos*8 + cg
    const int t = widx - 1728;
    const int j = t / 968, r = t % 968, pos = r >> 3, cg = r & 7;
    unsigned wrd = 0;
#pragma unroll
    for (int b = 0; b < 4; ++b) {
      const float v = wfc[j * 3872 + (cg * 4 + b) * 121 + pos];
      wrd |= ((unsigned)(uint8_t)(int8_t)sgn_pack_byte(v)) << (8 * b);
    }
    dst[widx] = (int)wrd;
  }
}

// ---------------------------------------------------------------------------
// Dispatch 2 -- k_forward: ONE image per block. LDS 20456 B -> 8 blocks/CU.
// ---------------------------------------------------------------------------
__global__ __launch_bounds__(256) void k_forward(
    const float* __restrict__ x, const float* __restrict__ w1,
    const int* __restrict__ wsd,  // d_ws base (dword-indexed)
    float* __restrict__ out, int B) {
  __shared__ __align__(16) char smem[20456];
  int* out_acc = (int*)(smem + 20416);  // [10]

  const int* wpack = wsd + 128;          // w2m | w3m (w3m at wpack+576)
  const int* sw = wsd + 1856;            // [10][968] dw
  const float* badj = (const float*)(wsd + 64);

  const int tid = threadIdx.x;
  const int img = blockIdx.x;

  // Early: this lane's wsmax slot (atomic-only line; poison is negative).
  const float slotv = __uint_as_float((unsigned)wsd[tid & 31]);

  // Stage: x -> xs @10816 via float4 (196 f4), w1t @13952, out_acc.
  {
    const float4* x4 = (const float4*)(x + (size_t)img * 784);
    if (tid < 196) *(float4*)(smem + 10816 + tid * 16) = x4[tid];
  }
  if (tid < 144) *(float*)(smem + 13952 + ((tid % 9) * 16 + tid / 9) * 4) = w1[tid];
  if (tid < 10) out_acc[tid] = 0;
  __syncthreads();

  // Phase 1: conv1 -> a1 = (s+1) in {0,1,2}. Vertical 3-px strips (R22).
  // Scale = wave-butterfly max over the 32 slots (fmax reorder is exact).
  float mraw = slotv;
#pragma unroll
  for (int off = 16; off; off >>= 1) mraw = fmaxf(mraw, __shfl_xor(mraw, off, 64));
  const float scale = mraw / 127.0f + 1e-8f;
  const float thr = 0.5f * scale;
  {
    const f2* w1t2 = (const f2*)(smem + 13952);
    const bool pact = tid < 234;
    const int ox = pact ? (tid % 26) : 0;
    const int g = pact ? (tid / 26) : 0;
    const int oy0 = g * 3;
    const int npx = pact ? ((oy0 <= 23) ? 3 : 26 - oy0) : 0;  // g=8 -> 2
    const char* bx = smem + 10816 + (oy0 * 28 + ox) * 4;
    const int r4 = (oy0 + 4 < 28) ? 4 : 3;  // clamp feeds only guarded-out px
    unsigned wq[3][4];
#pragma unroll
    for (int ch = 0; ch < 4; ++ch) {
      f2 wa[9], wb9[9];
#pragma unroll
      for (int i = 0; i < 9; ++i) {
        wa[i] = w1t2[i * 8 + 2 * ch];      // channels 4ch+0,4ch+1
        wb9[i] = w1t2[i * 8 + 2 * ch + 1]; // channels 4ch+2,4ch+3
      }
      if (pact) {
        float xw2[15];
#pragma unroll
        for (int r = 0; r < 5; ++r) {
          const int rr = (r < 4) ? r : r4;
#pragma unroll
          for (int c = 0; c < 3; ++c)
            xw2[r * 3 + c] = *(const float*)(bx + (rr * 28 + c) * 4);
        }
#pragma unroll
        for (int s = 0; s < 3; ++s) {
          if (s < npx) {
            f2 h0 = {0.f, 0.f}, h1 = {0.f, 0.f};
#pragma unroll
            for (int i = 0; i < 9; ++i) {
              const f2 sv = {xw2[s * 3 + i], xw2[s * 3 + i]};
              h0 += wa[i] * sv;
              h1 += wb9[i] * sv;
            }
            // (s+1): 0 iff h < -thr, 1 iff |h| <= thr, 2 iff h > thr.
            wq[s][ch] = (unsigned)pack4(
                (h0.x >= -thr) + (h0.x > thr), (h0.y >= -thr) + (h0.y > thr),
                (h1.x >= -thr) + (h1.x > thr), (h1.y >= -thr) + (h1.y > thr));
          }
        }
      }
    }
#pragma unroll
    for (int s = 0; s < 3; ++s)
      if (s < npx)
        *(int4*)(smem + ((oy0 + s) * 26 + ox) * 16) =
            make_int4((int)wq[s][0], (int)wq[s][1], (int)wq[s][2], (int)wq[s][3]);
  }
  __syncthreads();

  // MFMA lane geometry. t=2 uses wp=8 for ALL quads (dead-B broadcast:
  // quads 1-3 have zero-A so values are ignored; same-address read is free).
  const int lane = tid & 63, wv = tid >> 6;
  const int col = lane & 15, quad = lane >> 4;
  int off2[3], off3[3];
#pragma unroll
  for (int t = 0; t < 3; ++t) {
    const int wp = (t < 2) ? (t * 4 + quad) : 8;
    const int wr = wp / 3, wc = wp - wr * 3;
    off2[t] = (wr * 26 + wc) * 16;  // a1 stride 26 px
    off3[t] = (wr * 25 + wc) * 16;  // h2 stride 25 px
  }
  const bool kq0 = (quad == 0);

  // Phase 2: conv2, UNROLLED with closed-form per-iteration addresses
  // (p = p0 + 64*it) — all 9 iterations independent, ds_reads pipelineable.
  {
    const int* wb = wpack + col * 36;  // A-row oc = col
    int4v WA[3];
    WA[0] = *(const int4v*)(wb + quad * 4);
    WA[1] = *(const int4v*)(wb + 16 + quad * 4);
    WA[2] = kq0 ? *(const int4v*)(wb + 32) : (int4v){0, 0, 0, 0};
    const int4v acc0 = (int4v){1, 1, 1, 1} - *(const int4v*)(wsd + 80 + quad * 4);
    const int8_t* a1b = (const int8_t*)smem;
    const int p0 = wv * 16 + col;
#pragma unroll
    for (int it = 0; it < 9; ++it) {
      const int p = p0 + it * 64;
      const int oy = p / 24, ox = p - oy * 24;
      const int8_t* abase = a1b + (oy * 26 + ox) * 16;
      int* h2p = (int*)smem + 2704 + (oy * 25 + ox) * 4 + quad;
      int4v acc = acc0;
      acc = mfma_i8(WA[0], *(const int4v*)(abase + off2[0]), acc);
      acc = mfma_i8(WA[1], *(const int4v*)(abase + off2[1]), acc);
      acc = mfma_i8(WA[2], *(const int4v*)(abase + off2[2]), acc);
      *h2p = pack4(cl02(acc[0]), cl02(acc[1]), cl02(acc[2]), cl02(acc[3]));
    }
  }
  __syncthreads();

  // Phase 3: conv3 + in-register pool, UNROLLED with closed-form addresses:
  // cell = cell0 + 16u, ce = min(cell,120) (== old aoff/pb clamps exactly).
  {
    int4v WA[2][3];
    int4v ac0[2];
#pragma unroll
    for (int ot = 0; ot < 2; ++ot) {
      const int* wb = wpack + 576 + (ot * 16 + col) * 36;
      WA[ot][0] = *(const int4v*)(wb + quad * 4);
      WA[ot][1] = *(const int4v*)(wb + 16 + quad * 4);
      WA[ot][2] = kq0 ? *(const int4v*)(wb + 32) : (int4v){0, 0, 0, 0};
      ac0[ot] = (int4v){1, 1, 1, 1} - *(const int4v*)(wsd + 96 + ot * 16 + quad * 4);
    }
    const int sub = col & 3;
    const int sy = sub >> 1, sx = sub & 1;
    const int cell0 = wv * 4 + (col >> 2);
    const bool wlane = (sub == 0);
    const int8_t* h2b = (const int8_t*)(smem + 10816);
    int* p4 = (int*)smem;
#pragma unroll
    for (int u = 0; u < 8; ++u) {
      const int pt = wv + u * 4;
      if (pt < 31) {  // wave-uniform guard (wv=3 runs 7 iterations)
        const int cell = cell0 + u * 16;
        const int ce = (cell < 120) ? cell : 120;
        const int cy = ce / 11, cx = ce - cy * 11;
        const int8_t* abase = h2b + ((cy * 2 + sy) * 25 + cx * 2 + sx) * 16;
        const int pbu = ce * 12 + quad;
        const int4v B0 = *(const int4v*)(abase + off3[0]);
        const int4v B1 = *(const int4v*)(abase + off3[1]);
        const int4v B2 = *(const int4v*)(abase + off3[2]);
#pragma unroll
        for (int ot = 0; ot < 2; ++ot) {
          int4v acc = ac0[ot];
          acc = mfma_i8(WA[ot][0], B0, acc);
          acc = mfma_i8(WA[ot][1], B1, acc);
          acc = mfma_i8(WA[ot][2], B2, acc);
          int s = pack4(cl02(acc[0]), cl02(acc[1]), cl02(acc[2]), cl02(acc[3]));
          // sum (s3+1) packed bytes across the lane nibble (cell's 2x2)
          s += __builtin_amdgcn_update_dpp(0, s, 0xB1, 0xF, 0xF, false);
          s += __builtin_amdgcn_update_dpp(0, s, 0x4E, 0xF, 0xF, false);
          if (wlane) p4[pbu + ot * 4] = s;
        }
      }
    }
  }
  __syncthreads();

  // Phase 4: FC, UNROLLED (pos = k + 25m, guard pos<121 reproduces the
  // 4/5-trip variation). acc = sum n*sw; badj corrects.
  if (tid < 250) {
    const int j = tid % 10, k = tid / 10;
    const int* p4d = (const int*)smem;
    int acc = 0;
#pragma unroll
    for (int m = 0; m < 5; ++m) {
      const int pos = k + m * 25;
      if (pos < 121) {
        const int4 pa = *(const int4*)(p4d + pos * 12);
        const int4 pb = *(const int4*)(p4d + pos * 12 + 4);
        const int* swr = sw + j * 968 + pos * 8;
        const int4 wa = *(const int4*)(swr);
        const int4 wbv = *(const int4*)(swr + 4);
        acc = dot4(pa.x, wa.x, acc);
        acc = dot4(pa.y, wa.y, acc);
        acc = dot4(pa.z, wa.z, acc);
        acc = dot4(pa.w, wa.w, acc);
        acc = dot4(pb.x, wbv.x, acc);
        acc = dot4(pb.y, wbv.y, acc);
        acc = dot4(pb.z, wbv.z, acc);
        acc = dot4(pb.w, wbv.w, acc);
      }
    }
    atomicAdd(&out_acc[j], acc);
  }
  __syncthreads();
  if (tid < 10)
    out[(size_t)img * 10 + tid] = 0.25f * (float)out_acc[tid] + badj[tid];
}

extern "C" void kernel_launch(void* const* d_in, const int* in_sizes, int n_in,
                              void* d_out, int out_size, void* d_ws, size_t ws_size,
                              hipStream_t stream) {
  const float* x   = (const float*)d_in[0];
  const float* w1  = (const float*)d_in[1];
  const float* w2  = (const float*)d_in[2];
  const float* w3  = (const float*)d_in[3];
  const float* wfc = (const float*)d_in[4];
  const float* bfc = (const float*)d_in[5];
  float* out = (float*)d_out;
  int* wsd = (int*)d_ws;
  const int B = in_sizes[0] / 784;
  const int NMAX = (B + 1) / 2;

  hipLaunchKernelGGL(k_prep_max, dim3(NMAX + 56), dim3(256), 0, stream,
                     x, w1, w2, w3, wfc, bfc, wsd, B, NMAX);
  hipLaunchKernelGGL(k_forward, dim3(B), dim3(256), 0, stream, x, w1,
                     (const int*)wsd, out, B);
}

// Round 11
// 190.544 us; speedup vs baseline: 1.0432x; 1.0273x over previous
//
#include <hip/hip_runtime.h>
#include <stdint.h>

// ---------------------------------------------------------------------------
// Binarized QAT CNN forward (R24 = R19 locked in as final; best measured).
//   FINAL SCOREBOARD (forward dur): R19 97.5 (best) | R20 100.4 (VGPR loss)
//   | R22 98.0 (LDS-cut null) | R23 99.8 (unroll null). All levers tested:
//   VALU trims null, LDS-inst cuts null at const VGPR, conflicts 12M->8.6M
//   no effect, ILP unroll null. Counters pinned: VALUBusy ~80%, MfmaUtil
//   ~17%, HBM ~1.8% -> VALU-issue-bound. Ceiling arithmetic: fp32 conv1
//   (676px x 16ch x 9tap, f2-packed = 72 pk-fma + ~64 exact-threshold ops +
//   12 packs per px) is numerics-pinned (R8) and has NO fp32 MFMA path on
//   CDNA4; it is computed TWICE (prep needs global absmax before any
//   quantize; no device-wide sync available: coop fails under graph capture
//   [R12], spin-barrier violates G16 residency rules). Phases 2-4 already
//   i8-MFMA-ized (matrix pipe 83% idle, not the constraint).
//   - R18 LESSON: XOR-by-row-parity LDS swizzle is NON-BIJECTIVE at
//     non-128-mult row strides (16p ^ 64 = 16(p^4) crosses rows) — never
//     re-add without padding rows to 128-mult.
//   - R20 LESSON: VGPR >44 costs more (occupancy/latency-hiding) than any
//     LDS/VALU savings bought in this kernel.
//
// HARNESS RULE (R12): hipLaunchCooperativeKernel silently fails under graph
// capture here. Two plain dispatches are the minimum; do not retry coop.
// RACE RULE (R8/R9, confirmed R10): the wsmax line (d_ws bytes 0..255) is
// touched ONLY by signed atomicMax (0xAA poison is negative -> loses, so no
// zeroing store exists anywhere); all prep plain-stores live at byte >= 256.
// Slots 0..31 all atomic-only; untouched slots stay poison (negative float,
// loses the fmax reduce in k_forward).
// NUMERICS RULE (R8): conv1 must keep the exact pk-fma form (h += w*s,
// i ascending, LDS-staged weight values) in BOTH kernels — scalar-chain
// rewrites flip boundary decisions.
// NOTE: plain __launch_bounds__(256) — a min-waves arg caps arch VGPRs and
// spills ~50 dw/thread (R4: 426 MB scratch writes). Do not re-add it.
//
// MFMA i8 16x16x64 lane mapping (gfx950): A: lane l holds A[m=l&15][k=16q+j];
// B: B[k=16q+j][n=l&15]; D reg r: row=(l>>4)*4+r, col=l&15. A=weights =>
// A-row oc = col; lane's 4 D values = 4 consecutive channels of one pixel.
// K=144 padded to 192 by zeroing the WEIGHT fragment for k-blocks 9..11.
//
// d_ws layout (dwords): [0..31] wsmax slots (atomic-only line) |
//   [64..73] badj f32[10] | [80..95] rs2 | [96..127] rs3 | [128..703] w2m |
//   [704..1855] w3m | [1856..11535] sw   (total 46144 B)
//
// k_forward LDS map (20456 B, 8 blocks/CU):
//   a1 [0, 10816): 26x26 px x 16 B; p4 [121 cells x 48 B = 5808 B] aliases
//     head (a1 dead in phases 3+).
//   h2 [10816, 20416): 24 rows x 25 px x 16 B (col 24 = pad); xs [3136 B] +
//     w1t [576 B] alias head during phases 0-1.
//   out_acc @20416 (40 B).
// ---------------------------------------------------------------------------

typedef int int4v __attribute__((ext_vector_type(4)));
typedef float f2 __attribute__((ext_vector_type(2)));

__device__ __forceinline__ int4v mfma_i8(int4v a, int4v b, int4v c) {
  return __builtin_amdgcn_mfma_i32_16x16x64_i8(a, b, c, 0, 0, 0);
}

__device__ __forceinline__ int dot4(int a, int b, int c) {
#if __has_builtin(__builtin_amdgcn_sdot4)
  return __builtin_amdgcn_sdot4(a, b, c, false);
#else
  int r = c;
  r += (int)(int8_t)(a)       * (int)(int8_t)(b);
  r += (int)(int8_t)(a >> 8)  * (int)(int8_t)(b >> 8);
  r += (int)(int8_t)(a >> 16) * (int)(int8_t)(b >> 16);
  r += (int)(int8_t)(a >> 24) * (int)(int8_t)(b >> 24);
  return r;
#endif
}

// Pack low bytes of r0..r3 into one dword: [r0b0|r1b0|r2b0|r3b0].
__device__ __forceinline__ int pack4(int r0, int r1, int r2, int r3) {
  const int t0 = __builtin_amdgcn_perm(r1, r0, 0x00000400);
  const int t1 = __builtin_amdgcn_perm(r3, r2, 0x00000400);
  return __builtin_amdgcn_perm(t1, t0, 0x05040100);
}

// med3(v,0,2) in one VALU op; acc init carries the +1 so this is the epilogue.
__device__ __forceinline__ int cl02(int v) {
  int r;
  asm("v_med3_i32 %0, %1, 0, 2" : "=v"(r) : "v"(v));
  return r;
}

__device__ __forceinline__ int sgn_pack_byte(float v) {
  return (v > 0.f) - (v < 0.f);
}

// Dispatch 1 -- merged conv1-max + prep (unchanged from R15).
__global__ __launch_bounds__(256) void k_prep_max(
    const float* __restrict__ x, const float* __restrict__ w1,
    const float* __restrict__ w2, const float* __restrict__ w3,
    const float* __restrict__ wfc, const float* __restrict__ bfc,
    int* __restrict__ ws, int B, int NMAX) {
  __shared__ __align__(16) float xs[1568];
  __shared__ __align__(8) float w1t[144];
  __shared__ float wred[4];
  __shared__ int part[4];

  const int tid = threadIdx.x;
  if ((int)blockIdx.x < NMAX) {
    const int img0 = blockIdx.x * 2;
    const bool has1 = (img0 + 1) < B;
    {
      const float4* x4a = (const float4*)(x + (size_t)img0 * 784);
      const float4* x4b = (const float4*)(x + (size_t)(img0 + (int)has1) * 784);
      for (int u = tid; u < 392; u += 256) {
        const int im = (u >= 196), i = im ? u - 196 : u;
        const float4 v = im ? x4b[i] : x4a[i];
        *(float4*)&xs[im * 784 + i * 4] = v;
      }
    }
    if (tid < 144) w1t[(tid % 9) * 16 + tid / 9] = w1[tid];
    __syncthreads();
    const f2* w1t2 = (const f2*)w1t;
    const float* xs0 = xs;
    const float* xs1 = xs + 784;
    float m = 0.f;
    for (int px = tid; px < 676; px += 256) {
      const int oy = px / 26, ox = px - oy * 26;
      float xw0[9], xw1[9];
#pragma unroll
      for (int r = 0; r < 3; ++r)
#pragma unroll
        for (int cc = 0; cc < 3; ++cc) {
          const int ix = (oy + r) * 28 + ox + cc;
          xw0[r * 3 + cc] = xs0[ix];
          xw1[r * 3 + cc] = xs1[ix];
        }
#pragma unroll
      for (int cw = 0; cw < 8; ++cw) {
        f2 h0 = {0.f, 0.f}, h1 = {0.f, 0.f};
#pragma unroll
        for (int i = 0; i < 9; ++i) {
          const f2 w = w1t2[i * 8 + cw];
          const f2 s0 = {xw0[i], xw0[i]};
          const f2 s1 = {xw1[i], xw1[i]};
          h0 += w * s0;
          h1 += w * s1;
        }
        m = fmaxf(m, fmaxf(fmaxf(fabsf(h0.x), fabsf(h0.y)),
                           fmaxf(fabsf(h1.x), fabsf(h1.y))));
      }
    }
#pragma unroll
    for (int off = 32; off; off >>= 1) m = fmaxf(m, __shfl_down(m, off, 64));
    if ((tid & 63) == 0) wred[tid >> 6] = m;
    __syncthreads();
    if (tid == 0) {
      const float mm = fmaxf(fmaxf(wred[0], wred[1]), fmaxf(wred[2], wred[3]));
      atomicMax(ws + ((int)blockIdx.x & 31), (int)__float_as_uint(mm));
    }
    return;
  }

  const int pb = blockIdx.x - NMAX;  // prep block id 0..55
  if (pb < 10) {
    const int j = pb;
    int s = 0;
    for (int i = tid; i < 3872; i += 256) {
      const float v = wfc[j * 3872 + i];
      s += (v > 0.f) - (v < 0.f);
    }
#pragma unroll
    for (int off = 32; off; off >>= 1) s += __shfl_down(s, off, 64);
    if ((tid & 63) == 0) part[tid >> 6] = s;
    __syncthreads();
    if (tid == 0) {
      const int rs = part[0] + part[1] + part[2] + part[3];
      ((float*)ws)[64 + j] = bfc[j] - (float)rs;  // badj @ dword 64 (byte 256)
    }
    if (pb == 1 && tid < 16) {  // rs2[oc] @ dword 80
      int s2 = 0;
      for (int i = 0; i < 144; ++i) s2 += sgn_pack_byte(w2[tid * 144 + i]);
      ws[80 + tid] = s2;
    }
    if (pb == 2 && tid < 32) {  // rs3[oc] @ dword 96
      int s3 = 0;
      for (int i = 0; i < 144; ++i) s3 += sgn_pack_byte(w3[tid * 144 + i]);
      ws[96 + tid] = s3;
    }
    return;
  }
  int* dst = ws + 128;
  const int widx = (pb - 10) * 256 + tid;
  if (widx < 576) {  // w2m: dword = oc*36 + wp*4 + icg
    const int oc = widx / 36, r = widx % 36, wp = r >> 2, icg = r & 3;
    unsigned wrd = 0;
#pragma unroll
    for (int b = 0; b < 4; ++b) {
      const float v = w2[(oc * 16 + icg * 4 + b) * 9 + wp];
      wrd |= ((unsigned)(uint8_t)(int8_t)sgn_pack_byte(v)) << (8 * b);
    }
    dst[widx] = (int)wrd;
  } else if (widx < 1728) {  // w3m
    const int t = widx - 576;
    const int oc = t / 36, r = t % 36, wp = r >> 2, icg = r & 3;
    unsigned wrd = 0;
#pragma unroll
    for (int b = 0; b < 4; ++b) {
      const float v = w3[(oc * 16 + icg * 4 + b) * 9 + wp];
      wrd |= ((unsigned)(uint8_t)(int8_t)sgn_pack_byte(v)) << (8 * b);
    }
    dst[widx] = (int)wrd;
  } else if (widx < 11408) {  // sw: dword = j*968 + pos*8 + cg
    const int t = widx - 1728;
    const int j = t / 968, r = t % 968, pos = r >> 3, cg = r & 7;
    unsigned wrd = 0;
#pragma unroll
    for (int b = 0; b < 4; ++b) {
      const float v = wfc[j * 3872 + (cg * 4 + b) * 121 + pos];
      wrd |= ((unsigned)(uint8_t)(int8_t)sgn_pack_byte(v)) << (8 * b);
    }
    dst[widx] = (int)wrd;
  }
}

// ---------------------------------------------------------------------------
// Dispatch 2 -- k_forward: ONE image per block. LDS 20456 B -> 8 blocks/CU.
// ---------------------------------------------------------------------------
__global__ __launch_bounds__(256) void k_forward(
    const float* __restrict__ x, const float* __restrict__ w1,
    const int* __restrict__ wsd,  // d_ws base (dword-indexed)
    float* __restrict__ out, int B) {
  __shared__ __align__(16) char smem[20456];
  int* out_acc = (int*)(smem + 20416);  // [10]

  const int* wpack = wsd + 128;          // w2m | w3m (w3m at wpack+576)
  const int* sw = wsd + 1856;            // [10][968] dw
  const float* badj = (const float*)(wsd + 64);

  const int tid = threadIdx.x;
  const int img = blockIdx.x;

  // Early: this lane's wsmax slot (atomic-only line; poison is negative).
  const float slotv = __uint_as_float((unsigned)wsd[tid & 31]);

  // Stage: x -> xs @10816 via float4 (196 f4), w1t @13952, out_acc.
  {
    const float4* x4 = (const float4*)(x + (size_t)img * 784);
    if (tid < 196) *(float4*)(smem + 10816 + tid * 16) = x4[tid];
  }
  if (tid < 144) *(float*)(smem + 13952 + ((tid % 9) * 16 + tid / 9) * 4) = w1[tid];
  if (tid < 10) out_acc[tid] = 0;
  __syncthreads();

  // Phase 1: conv1 -> a1 = (s+1) in {0,1,2}. cw chunks of 2, weights hoisted
  // to regs (chunk outer, px inner); per-channel fma chain identical to prep:
  // h += w*s, i ascending, f2 pk form, LDS-staged weight values.
  // Scale = wave-butterfly max over the 32 slots (fmax reorder is exact).
  float mraw = slotv;
#pragma unroll
  for (int off = 16; off; off >>= 1) mraw = fmaxf(mraw, __shfl_xor(mraw, off, 64));
  const float scale = mraw / 127.0f + 1e-8f;
  const float thr = 0.5f * scale;
  {
    const f2* w1t2 = (const f2*)(smem + 13952);
    int xsb[3], a1o[3];
    bool act[3];
#pragma unroll
    for (int pi = 0; pi < 3; ++pi) {
      const int px = tid + pi * 256;
      act[pi] = px < 676;
      const int oy = px / 26, ox = px - oy * 26;
      xsb[pi] = 10816 + (oy * 28 + ox) * 4;
      a1o[pi] = px * 16;
    }
    unsigned wq[3][4];
#pragma unroll
    for (int ch = 0; ch < 4; ++ch) {
      f2 wa[9], wb9[9];
#pragma unroll
      for (int i = 0; i < 9; ++i) {
        wa[i] = w1t2[i * 8 + 2 * ch];      // channels 4ch+0,4ch+1
        wb9[i] = w1t2[i * 8 + 2 * ch + 1]; // channels 4ch+2,4ch+3
      }
#pragma unroll
      for (int pi = 0; pi < 3; ++pi) {
        if (act[pi]) {
          const char* bp = smem + xsb[pi];
          float xw[9];
#pragma unroll
          for (int r = 0; r < 3; ++r)
#pragma unroll
            for (int cc = 0; cc < 3; ++cc)
              xw[r * 3 + cc] = *(const float*)(bp + r * 112 + cc * 4);
          f2 h0 = {0.f, 0.f}, h1 = {0.f, 0.f};
#pragma unroll
          for (int i = 0; i < 9; ++i) {
            const f2 s = {xw[i], xw[i]};
            h0 += wa[i] * s;
            h1 += wb9[i] * s;
          }
          // (s+1): 0 iff h < -thr, 1 iff |h| <= thr, 2 iff h > thr.
          const int b0 = (h0.x >= -thr) + (h0.x > thr);
          const int b1 = (h0.y >= -thr) + (h0.y > thr);
          const int b2 = (h1.x >= -thr) + (h1.x > thr);
          const int b3 = (h1.y >= -thr) + (h1.y > thr);
          wq[pi][ch] = (unsigned)pack4(b0, b1, b2, b3);
        }
      }
    }
#pragma unroll
    for (int pi = 0; pi < 3; ++pi)
      if (act[pi])
        *(int4*)(smem + a1o[pi]) =
            make_int4((int)wq[pi][0], (int)wq[pi][1], (int)wq[pi][2], (int)wq[pi][3]);
  }
  __syncthreads();

  // MFMA lane geometry. t=2 uses wp=8 for ALL quads (dead-B broadcast:
  // quads 1-3 have zero-A so values are ignored; same-address read is free
  // and keeps the operand inside the live region).
  const int lane = tid & 63, wv = tid >> 6;
  const int col = lane & 15, quad = lane >> 4;
  int off2[3], off3[3];
#pragma unroll
  for (int t = 0; t < 3; ++t) {
    const int wp = (t < 2) ? (t * 4 + quad) : 8;
    const int wr = wp / 3, wc = wp - wr * 3;
    off2[t] = (wr * 26 + wc) * 16;  // a1 stride 26 px
    off3[t] = (wr * 25 + wc) * 16;  // h2 stride 25 px
  }
  const bool kq0 = (quad == 0);

  // Phase 2: conv2. A=sign(w2) frags; acc init = 1 - rs2 (the +1 feeds cl02).
  // h2 written with padded row stride 25 px (400 B).
  {
    const int* wb = wpack + col * 36;  // A-row oc = col
    int4v WA[3];
    WA[0] = *(const int4v*)(wb + quad * 4);
    WA[1] = *(const int4v*)(wb + 16 + quad * 4);
    WA[2] = kq0 ? *(const int4v*)(wb + 32) : (int4v){0, 0, 0, 0};
    const int4v acc0 = (int4v){1, 1, 1, 1} - *(const int4v*)(wsd + 80 + quad * 4);
    const int8_t* a1b = (const int8_t*)smem;
    // incremental (oy,ox) over output pixel p = nt*16+col, nt += 4 (p += 64)
    const int p0 = wv * 16 + col;
    int oy = p0 / 24, ox = p0 - oy * 24;
    const int8_t* abase = a1b + (oy * 26 + ox) * 16;
    int* h2p = (int*)smem + 2704 + (oy * 25 + ox) * 4 + quad;
    for (int it = 0; it < 9; ++it) {
      int4v acc = acc0;
      acc = mfma_i8(WA[0], *(const int4v*)(abase + off2[0]), acc);
      acc = mfma_i8(WA[1], *(const int4v*)(abase + off2[1]), acc);
      acc = mfma_i8(WA[2], *(const int4v*)(abase + off2[2]), acc);
      *h2p = pack4(cl02(acc[0]), cl02(acc[1]), cl02(acc[2]), cl02(acc[3]));
      abase += 1088;  // a1: (oy+=2, ox+=16), stride 26
      h2p += 264;     // h2: (oy+=2, ox+=16), stride 25 (dwords)
      ox += 16;
      if (ox >= 24) { ox -= 24; abase += 32; h2p += 4; }
    }
  }
  __syncthreads();

  // Phase 3: conv3 + in-register pool. Pixels tiled pool-quad-major:
  // tile pt covers cells 4pt..4pt+3; lane col -> cell 4pt+(col>>2), sub col&3.
  // p4 (48 B/cell stride) is written into the a1 region (a1 dead).
  {
    int4v WA[2][3];
    int4v ac0[2];
#pragma unroll
    for (int ot = 0; ot < 2; ++ot) {
      const int* wb = wpack + 576 + (ot * 16 + col) * 36;
      WA[ot][0] = *(const int4v*)(wb + quad * 4);
      WA[ot][1] = *(const int4v*)(wb + 16 + quad * 4);
      WA[ot][2] = kq0 ? *(const int4v*)(wb + 32) : (int4v){0, 0, 0, 0};
      ac0[ot] = (int4v){1, 1, 1, 1} - *(const int4v*)(wsd + 96 + ot * 16 + quad * 4);
    }
    const int sub = col & 3;
    const int sy = sub >> 1, sx = sub & 1;
    const int cell0 = wv * 4 + (col >> 2);
    const int cy0 = cell0 / 11, cx0 = cell0 - cy0 * 11;
    const int aoff0 = ((cy0 * 2 + sy) * 25 + cx0 * 2 + sx) * 16;
    const int pb0 = cell0 * 12 + quad;
    const int aoffcap = ((20 + sy) * 25 + 20 + sx) * 16;  // cell 120 clamp
    const int pbcap = 120 * 12 + quad;
    const bool wlane = (sub == 0);
    const int8_t* h2b = (const int8_t*)(smem + 10816);
    int* p4 = (int*)smem;
    int aoff = aoff0, pb = pb0, cx = cx0;
    for (int pt = wv; pt < 31; pt += 4) {
      const int8_t* abase = h2b + ((aoff < aoffcap) ? aoff : aoffcap);
      const int pbu = (pb < pbcap) ? pb : pbcap;
      const int4v B0 = *(const int4v*)(abase + off3[0]);
      const int4v B1 = *(const int4v*)(abase + off3[1]);
      const int4v B2 = *(const int4v*)(abase + off3[2]);
#pragma unroll
      for (int ot = 0; ot < 2; ++ot) {
        int4v acc = ac0[ot];
        acc = mfma_i8(WA[ot][0], B0, acc);
        acc = mfma_i8(WA[ot][1], B1, acc);
        acc = mfma_i8(WA[ot][2], B2, acc);
        int s = pack4(cl02(acc[0]), cl02(acc[1]), cl02(acc[2]), cl02(acc[3]));
        // sum (s3+1) packed bytes across the lane nibble (cell's 2x2)
        s += __builtin_amdgcn_update_dpp(0, s, 0xB1, 0xF, 0xF, false);
        s += __builtin_amdgcn_update_dpp(0, s, 0x4E, 0xF, 0xF, false);
        if (wlane) p4[pbu + ot * 4] = s;
      }
      aoff += 960;  // cell += 16: (cy+=1, cx+=5), stride 25
      pb += 192;    // cell += 16, stride 12 dw
      cx += 5;
      if (cx >= 11) { cx -= 11; aoff += 448; }
    }
  }
  __syncthreads();

  // Phase 4: FC. acc = sum n*sw = 4*true + 4*rowsum(sw); badj corrects.
  // Mapping j=u%10, k=u/10: 10 lanes share each pos (LDS broadcast reads,
  // conflict-free with the 48 B cell stride); atomics 7-way per out_acc[j].
  if (tid < 250) {
    const int j = tid % 10, k = tid / 10;
    const int* p4d = (const int*)smem;
    int acc = 0;
    for (int pos = k; pos < 121; pos += 25) {
      const int4 pa = *(const int4*)(p4d + pos * 12);
      const int4 pb = *(const int4*)(p4d + pos * 12 + 4);
      const int* swr = sw + j * 968 + pos * 8;
      const int4 wa = *(const int4*)(swr);
      const int4 wbv = *(const int4*)(swr + 4);
      acc = dot4(pa.x, wa.x, acc);
      acc = dot4(pa.y, wa.y, acc);
      acc = dot4(pa.z, wa.z, acc);
      acc = dot4(pa.w, wa.w, acc);
      acc = dot4(pb.x, wbv.x, acc);
      acc = dot4(pb.y, wbv.y, acc);
      acc = dot4(pb.z, wbv.z, acc);
      acc = dot4(pb.w, wbv.w, acc);
    }
    atomicAdd(&out_acc[j], acc);
  }
  __syncthreads();
  if (tid < 10)
    out[(size_t)img * 10 + tid] = 0.25f * (float)out_acc[tid] + badj[tid];
}

extern "C" void kernel_launch(void* const* d_in, const int* in_sizes, int n_in,
                              void* d_out, int out_size, void* d_ws, size_t ws_size,
                              hipStream_t stream) {
  const float* x   = (const float*)d_in[0];
  const float* w1  = (const float*)d_in[1];
  const float* w2  = (const float*)d_in[2];
  const float* w3  = (const float*)d_in[3];
  const float* wfc = (const float*)d_in[4];
  const float* bfc = (const float*)d_in[5];
  float* out = (float*)d_out;
  int* wsd = (int*)d_ws;
  const int B = in_sizes[0] / 784;
  const int NMAX = (B + 1) / 2;

  hipLaunchKernelGGL(k_prep_max, dim3(NMAX + 56), dim3(256), 0, stream,
                     x, w1, w2, w3, wfc, bfc, wsd, B, NMAX);
  hipLaunchKernelGGL(k_forward, dim3(B), dim3(256), 0, stream, x, w1,
                     (const int*)wsd, out, B);
}